// Round 6
// baseline (254.288 us; speedup 1.0000x reference)
//
#include <hip/hip_runtime.h>

// ============================================================================
// MHAtt with geometric box positional bias — MI355X/gfx950. Round 6.
// B=32 N=256 DM=512 H=8 DH=64. Inputs f32, mask int32, outputs f32.
//
// Round-5 counters: gemm128 54.9us, MfmaUtil 8.6%, 3.1M LDS bank conflicts
// (pad-40 stride 80B is bank-non-uniform), no load/compute overlap.
// Round-6 fix: BK=64 (8 k-trips, 32 MFMA/barrier-pair), pad 72 elems
// (144B stride == 16 mod 128 -> perfect 8-start x 8-lane bank distribution
// for both b128 staging writes and frag reads), register-prefetch pipeline
// (tile kk+1 global loads issued right after barrier, in flight during MFMA).
// K-summation order unchanged -> bit-identical numerics to round 5.
//
// 5 dispatches: transpose, pos, gemm128<float> (QKV fused, z=3),
//               attn, gemm128<bf16> (final).
//
// MFMA 16x16x32 bf16 layouts (verified m89/m91 + round-3 scalar oracle):
//   A: lane holds A[m=lane&15][k=(lane>>4)*8+j]   (16B contiguous)
//   B: lane holds B[k=(lane>>4)*8+j][n=lane&15]   (contiguous, B stored n-major)
//   C/D: col=lane&15, row=(lane>>4)*4+reg
// ============================================================================

typedef __bf16 bf16_t;
typedef __bf16 bf16x8 __attribute__((ext_vector_type(8)));
typedef float  f32x4  __attribute__((ext_vector_type(4)));
typedef float  f32x8  __attribute__((ext_vector_type(8)));

#define NB    32
#define NSEQ  256
#define DMODEL 512
#define NH    8
#define DHEAD 64
#define M_ROWS (NB * NSEQ)              // 8192
#define ATTED_ELEMS (M_ROWS * DMODEL)   // 4,194,304 f32
#define HEAD_T_ELEMS 4194304            // elems of one [B,H,N,DH]-class tensor

// ws layout (bf16 elements); total 17,825,792 elems = 35.7 MB
#define WS_WT    0          // 4 * 512*512
#define WS_QH    1048576    // q: +0, k: +4.19M, vT: +8.39M
#define WS_ATTW  13631488   // [B*N, DM]

// raw 8-element vector per A dtype (load raw, convert at LDS-store time)
template <typename T> struct vec8;
template <> struct vec8<float>  { using type = f32x8; };
template <> struct vec8<bf16_t> { using type = bf16x8; };

__device__ inline bf16x8 to_bf16(bf16x8 v) { return v; }
__device__ inline bf16x8 to_bf16(f32x8 v) {
  bf16x8 r;
#pragma unroll
  for (int j = 0; j < 8; j++) r[j] = (bf16_t)v[j];
  return r;
}

// ---------------------------------------------------------------------------
// W (f32, [k][n]) -> WT (bf16, [n][k]), 64x64 LDS tiles, both sides coalesced.
__global__ __launch_bounds__(256) void transpose_kernel(
    const float* __restrict__ W0, const float* __restrict__ W1,
    const float* __restrict__ W2, const float* __restrict__ W3,
    bf16_t* __restrict__ wt) {
  __shared__ float T_s[64 * 65];
  int tid = threadIdx.x;
  int m = blockIdx.z;
  const float* W = (m == 0) ? W0 : (m == 1) ? W1 : (m == 2) ? W2 : W3;
  bf16_t* WT = wt + m * (DMODEL * DMODEL);
  int k0 = blockIdx.x * 64, n0 = blockIdx.y * 64;
#pragma unroll
  for (int i = 0; i < 16; i++) {
    int idx = tid + i * 256;
    int r = idx >> 6, c = idx & 63;
    T_s[r * 65 + c] = W[(size_t)(k0 + r) * DMODEL + n0 + c];
  }
  __syncthreads();
#pragma unroll
  for (int i = 0; i < 16; i++) {
    int idx = tid + i * 256;
    int r = idx >> 6, c = idx & 63;
    WT[(size_t)(n0 + r) * DMODEL + k0 + c] = (bf16_t)T_s[c * 65 + r];
  }
}

// ---------------------------------------------------------------------------
// ps[b,i,j]; one block per (b,i), thread j. Writes all 8 head copies (f32).
__global__ __launch_bounds__(256) void pos_kernel(
    const float* __restrict__ box, const float* __restrict__ Wbox,
    const float* __restrict__ bbox, float* __restrict__ pos_out) {
  __shared__ float wb[64];
  __shared__ float bb;
  int tid = threadIdx.x;
  if (tid < 64) wb[tid] = Wbox[tid];
  if (tid == 0) bb = bbox[0];
  __syncthreads();

  int bx = blockIdx.x;
  int b = bx >> 8, i = bx & 255, j = tid;

  float4 bi = *(const float4*)(box + (size_t)(b * NSEQ + i) * 4);
  float4 bj = *(const float4*)(box + (size_t)(b * NSEQ + j) * 4);

  float cxi = (bi.x + bi.z) * 0.5f, cyi = (bi.y + bi.w) * 0.5f;
  float wi = bi.z - bi.x + 1.0f,    hi = bi.w - bi.y + 1.0f;
  float cxj = (bj.x + bj.z) * 0.5f, cyj = (bj.y + bj.w) * 0.5f;
  float wj = bj.z - bj.x + 1.0f,    hj = bj.w - bj.y + 1.0f;

  float dx = __logf(fmaxf(fabsf((cxi - cxj) / wi), 1e-3f));
  float dy = __logf(fmaxf(fabsf((cyi - cyj) / hi), 1e-3f));
  float dw = __logf(wi / wj);
  float dh = __logf(hi / hj);

  // dim_mat[f] = 1000^(-f/8)
  const float dim_mat[8] = {1.0f, 0.42169650342f, 0.177827941f, 0.074989421f,
                            0.0316227766f, 0.0133352143f, 0.00562341325f, 0.00237137371f};
  float p4[4] = {dx, dy, dw, dh};
  float acc = bb;
#pragma unroll
  for (int c = 0; c < 4; c++) {
    float base = 100.0f * p4[c];
#pragma unroll
    for (int f = 0; f < 8; f++) {
      float sn, cs;
      __sincosf(base * dim_mat[f], &sn, &cs);
      acc += sn * wb[c * 8 + f] + cs * wb[32 + c * 8 + f];
    }
  }
  float pv = fmaxf(acc, 0.0f);
  size_t base_bi = ((size_t)b * NH * NSEQ + i) * NSEQ + j;  // h=0 slot
#pragma unroll
  for (int h = 0; h < NH; h++)
    pos_out[base_bi + (size_t)h * NSEQ * NSEQ] = pv;
}

// ---------------------------------------------------------------------------
// LDS-staged GEMM, 128x128 tile, BK=64, 4 waves (2x2 of 64x64), reg-prefetch
// pipeline. C[8192,512] = A @ W + bias, W pre-transposed bf16 (WT[n][k]).
// Rows padded to 72 bf16 (144 B): bank-start = 4*(row+seg) mod 32 -> uniform
// 8 starts x 8 lanes for every b128 LDS op (minimum phases, zero excess).
// final_mode==0: fused QKV (z selects input/bias/output; z==2 -> vT layout)
// final_mode==2: final projection (A=attw bf16, out f32 row-major)
template <typename AT>
__global__ __launch_bounds__(256) void gemm128_kernel(
    const AT* __restrict__ A0, const AT* __restrict__ A1, const AT* __restrict__ A2,
    const bf16_t* __restrict__ WTbase,
    const float* __restrict__ bias0, const float* __restrict__ bias1,
    const float* __restrict__ bias2,
    bf16_t* __restrict__ outb, float* __restrict__ outf, int final_mode) {
  __shared__ bf16_t A_s[128 * 72];
  __shared__ bf16_t B_s[128 * 72];

  int tid = threadIdx.x;
  int wave = tid >> 6, lane = tid & 63, quad = lane >> 4, l16 = lane & 15;
  int wm = wave >> 1, wn = wave & 1;
  int bm = blockIdx.x, bn = blockIdx.y, z = blockIdx.z;

  const AT* A = (z == 0) ? A0 : (z == 1) ? A1 : A2;
  const float* bias = (z == 0) ? bias0 : (z == 1) ? bias1 : bias2;
  const bf16_t* WT = WTbase + (size_t)(final_mode == 2 ? 3 : z) * 262144;
  int mode = (final_mode == 2) ? 2 : ((z == 2) ? 1 : 0);

  // staging assignment: 1024 8-elem segments; thread handles 4 (A) + 4 (B)
  int srow[4], sseg[4];
#pragma unroll
  for (int i = 0; i < 4; i++) {
    int flat = tid + i * 256;
    srow[i] = flat >> 3;
    sseg[i] = flat & 7;
  }

  typename vec8<AT>::type areg[4];
  bf16x8 breg[4];

  auto load_tiles = [&](int k0) {
#pragma unroll
    for (int i = 0; i < 4; i++) {
      areg[i] = *(const typename vec8<AT>::type*)
          (A + (size_t)(bm * 128 + srow[i]) * DMODEL + k0 + sseg[i] * 8);
      breg[i] = *(const bf16x8*)
          (WT + (size_t)(bn * 128 + srow[i]) * DMODEL + k0 + sseg[i] * 8);
    }
  };

  load_tiles(0);   // prologue

  f32x4 acc[4][4];
#pragma unroll
  for (int i = 0; i < 4; i++)
#pragma unroll
    for (int j = 0; j < 4; j++) acc[i][j] = (f32x4){0.f, 0.f, 0.f, 0.f};

  for (int kk = 0; kk < 8; kk++) {
    // commit staged regs to LDS (cvt f32->bf16 here for A)
#pragma unroll
    for (int i = 0; i < 4; i++) {
      *(bf16x8*)(A_s + srow[i] * 72 + sseg[i] * 8) = to_bf16(areg[i]);
      *(bf16x8*)(B_s + srow[i] * 72 + sseg[i] * 8) = breg[i];
    }
    __syncthreads();
    if (kk < 7) load_tiles((kk + 1) * 64);   // in flight during MFMA below

#pragma unroll
    for (int c = 0; c < 2; c++) {            // K=64 as two 32-chunks (order = round-5)
      bf16x8 a[4], b[4];
#pragma unroll
      for (int i = 0; i < 4; i++)
        a[i] = *(const bf16x8*)(A_s + (wm * 64 + i * 16 + l16) * 72 + c * 32 + quad * 8);
#pragma unroll
      for (int j = 0; j < 4; j++)
        b[j] = *(const bf16x8*)(B_s + (wn * 64 + j * 16 + l16) * 72 + c * 32 + quad * 8);
#pragma unroll
      for (int i = 0; i < 4; i++)
#pragma unroll
        for (int j = 0; j < 4; j++)
          acc[i][j] = __builtin_amdgcn_mfma_f32_16x16x32_bf16(a[i], b[j], acc[i][j], 0, 0, 0);
    }
    __syncthreads();
  }

  // epilogue
#pragma unroll
  for (int j = 0; j < 4; j++) {
    int gc = bn * 128 + wn * 64 + j * 16 + l16;
    float bs = bias[gc];
#pragma unroll
    for (int i = 0; i < 4; i++) {
#pragma unroll
      for (int r = 0; r < 4; r++) {
        int gm = bm * 128 + wm * 64 + i * 16 + quad * 4 + r;
        float val = acc[i][j][r] + bs;
        if (mode == 2) {
          outf[(size_t)gm * DMODEL + gc] = val;
        } else {
          int b = gm >> 8, n = gm & 255, h = gc >> 6, d = gc & 63;
          size_t idx = (mode == 0)
              ? ((size_t)(b * NH + h) * NSEQ + n) * DHEAD + d
              : ((size_t)(b * NH + h) * DHEAD + d) * NSEQ + n;
          outb[(size_t)z * HEAD_T_ELEMS + idx] = (bf16_t)val;
        }
      }
    }
  }
}

// ---------------------------------------------------------------------------
// Attention: block = (qt, h, b), 4 waves x 16 q-rows.
// K tile staged in LDS [256][72] (bank-uniform stride); P aliases it after
// phase A as [64][264]. Q frags + mask hoisted before staging (ILP).
__global__ __launch_bounds__(256) void attn_kernel(
    const bf16_t* __restrict__ qh, const bf16_t* __restrict__ kh,
    const bf16_t* __restrict__ vT, const float* __restrict__ pos,
    const int* __restrict__ mask, bf16_t* __restrict__ attw) {
  __shared__ bf16_t KP_s[256 * 72];   // 36,864 B; P (64x264) aliases it

  int tid = threadIdx.x;
  int wave = tid >> 6, lane = tid & 63, quad = lane >> 4, l16 = lane & 15;
  int qt = blockIdx.x, h = blockIdx.y, b = blockIdx.z;

  const bf16_t* qb = qh + (size_t)(b * NH + h) * NSEQ * DHEAD;
  const bf16_t* kb = kh + (size_t)(b * NH + h) * NSEQ * DHEAD;
  const bf16_t* vb = vT + (size_t)(b * NH + h) * DHEAD * NSEQ;
  const float* pb = pos + (size_t)b * NH * NSEQ * NSEQ;  // h=0 copy (identical)
  const int* mrow = mask + b * NSEQ;

  int m0 = qt * 64 + wave * 16;

  // hoisted independent loads: Q frags + mask row (overlap K staging latency)
  bf16x8 a0 = *(const bf16x8*)(qb + (size_t)(m0 + l16) * DHEAD + quad * 8);
  bf16x8 a1 = *(const bf16x8*)(qb + (size_t)(m0 + l16) * DHEAD + 32 + quad * 8);
  int mk[16];
#pragma unroll
  for (int t = 0; t < 16; t++) mk[t] = mrow[t * 16 + l16];

  // stage K tile: 256 rows x 64 d -> rows padded to 72
#pragma unroll
  for (int i = 0; i < 8; i++) {
    int flat = tid + i * 256;
    int row = flat >> 3, seg = flat & 7;
    *(bf16x8*)(KP_s + row * 72 + seg * 8) =
        *(const bf16x8*)(kb + (size_t)row * DHEAD + seg * 8);
  }
  __syncthreads();

  // Phase A: S = qh @ kh^T (16 key-tiles, K=64 as two 32-chunks) from LDS
  f32x4 s[16];
#pragma unroll
  for (int t = 0; t < 16; t++) s[t] = (f32x4){0.f, 0.f, 0.f, 0.f};
#pragma unroll
  for (int t = 0; t < 16; t++) {
    const bf16_t* krow = KP_s + (t * 16 + l16) * 72;
    bf16x8 b0 = *(const bf16x8*)(krow + quad * 8);
    bf16x8 b1 = *(const bf16x8*)(krow + 32 + quad * 8);
    s[t] = __builtin_amdgcn_mfma_f32_16x16x32_bf16(a0, b0, s[t], 0, 0, 0);
    s[t] = __builtin_amdgcn_mfma_f32_16x16x32_bf16(a1, b1, s[t], 0, 0, 0);
  }

  // Phase B: scale + pos + mask (C-layout: row=quad*4+r, col=t*16+l16)
#pragma unroll
  for (int t = 0; t < 16; t++) {
    int gj = t * 16 + l16;
#pragma unroll
    for (int r = 0; r < 4; r++) {
      int gr = m0 + quad * 4 + r;
      float v = s[t][r] * 0.125f + pb[(size_t)gr * NSEQ + gj];
      s[t][r] = mk[t] ? -1e9f : v;
    }
  }

  // Register softmax: each row lives across the 16 lanes of a quad.
  float inv[4];
#pragma unroll
  for (int r = 0; r < 4; r++) {
    float m = -1e30f;
#pragma unroll
    for (int t = 0; t < 16; t++) m = fmaxf(m, s[t][r]);
    m = fmaxf(m, __shfl_xor(m, 1));
    m = fmaxf(m, __shfl_xor(m, 2));
    m = fmaxf(m, __shfl_xor(m, 4));
    m = fmaxf(m, __shfl_xor(m, 8));
    float sum = 0.f;
#pragma unroll
    for (int t = 0; t < 16; t++) {
      float e = __expf(s[t][r] - m);
      s[t][r] = e;
      sum += e;
    }
    sum += __shfl_xor(sum, 1);
    sum += __shfl_xor(sum, 2);
    sum += __shfl_xor(sum, 4);
    sum += __shfl_xor(sum, 8);
    inv[r] = 1.0f / sum;
  }

  __syncthreads();   // all phase-A K_s reads complete before P overwrites

  // P (bf16) -> KP_s as [64][264] row-major (A-operand readable)
#pragma unroll
  for (int t = 0; t < 16; t++) {
    int gj = t * 16 + l16;
#pragma unroll
    for (int r = 0; r < 4; r++)
      KP_s[(wave * 16 + quad * 4 + r) * 264 + gj] = (bf16_t)(s[t][r] * inv[r]);
  }
  // no barrier: each wave reads back only its own 16 P rows

  // Phase C: O = P @ V (V pre-transposed [DH][N], direct global B-frags)
  f32x4 o[4];
#pragma unroll
  for (int t2 = 0; t2 < 4; t2++) o[t2] = (f32x4){0.f, 0.f, 0.f, 0.f};
#pragma unroll
  for (int kk = 0; kk < 8; kk++) {
    bf16x8 pa = *(const bf16x8*)(KP_s + (wave * 16 + l16) * 264 + kk * 32 + quad * 8);
#pragma unroll
    for (int t2 = 0; t2 < 4; t2++) {
      bf16x8 vv = *(const bf16x8*)(vb + (size_t)(t2 * 16 + l16) * NSEQ + kk * 32 + quad * 8);
      o[t2] = __builtin_amdgcn_mfma_f32_16x16x32_bf16(pa, vv, o[t2], 0, 0, 0);
    }
  }

  // Epilogue: attw[(b*256+q)*512 + h*64+d]
#pragma unroll
  for (int t2 = 0; t2 < 4; t2++) {
    int d = t2 * 16 + l16;
#pragma unroll
    for (int r = 0; r < 4; r++) {
      int gr = m0 + quad * 4 + r;
      attw[(size_t)(b * NSEQ + gr) * DMODEL + h * DHEAD + d] = (bf16_t)o[t2][r];
    }
  }
}

// ---------------------------------------------------------------------------
extern "C" void kernel_launch(void* const* d_in, const int* in_sizes, int n_in,
                              void* d_out, int out_size, void* d_ws, size_t ws_size,
                              hipStream_t stream) {
  const float* v    = (const float*)d_in[0];
  const float* k    = (const float*)d_in[1];
  const float* q    = (const float*)d_in[2];
  const float* box  = (const float*)d_in[3];
  const int*   mask = (const int*)d_in[4];
  // d_in[5] = fg (always 2; branch fixed)
  const float* Wq   = (const float*)d_in[6];
  const float* bq   = (const float*)d_in[7];
  const float* Wk   = (const float*)d_in[8];
  const float* bk   = (const float*)d_in[9];
  const float* Wv   = (const float*)d_in[10];
  const float* bv   = (const float*)d_in[11];
  const float* Wm   = (const float*)d_in[12];
  const float* bm   = (const float*)d_in[13];
  const float* Wbox = (const float*)d_in[14];
  const float* bbox = (const float*)d_in[15];

  float* out  = (float*)d_out;
  bf16_t* ws  = (bf16_t*)d_ws;
  bf16_t* WT   = ws + WS_WT;
  bf16_t* qh   = ws + WS_QH;
  bf16_t* khw  = qh + 1 * HEAD_T_ELEMS;
  bf16_t* vTp  = qh + 2 * HEAD_T_ELEMS;
  bf16_t* attw = ws + WS_ATTW;
  float* pos  = out + ATTED_ELEMS;   // pos_scores region (f32)

  transpose_kernel<<<dim3(8, 8, 4), dim3(256), 0, stream>>>(Wq, Wk, Wv, Wm, WT);
  pos_kernel<<<dim3(NB * NSEQ), dim3(256), 0, stream>>>(box, Wbox, bbox, pos);
  gemm128_kernel<float><<<dim3(64, 4, 3), dim3(256), 0, stream>>>(
      q, k, v, WT, bq, bk, bv, qh, out, 0);
  attn_kernel<<<dim3(NSEQ / 64, NH, NB), dim3(256), 0, stream>>>(
      qh, khw, vTp, pos, mask, attw);
  gemm128_kernel<bf16_t><<<dim3(64, 4, 1), dim3(256), 0, stream>>>(
      attw, attw, attw, WT, bm, bm, bm, qh, out, 2);
}

// Round 7
// 240.253 us; speedup vs baseline: 1.0584x; 1.0584x over previous
//
#include <hip/hip_runtime.h>

// ============================================================================
// MHAtt with geometric box positional bias — MI355X/gfx950. Round 7.
// B=32 N=256 DM=512 H=8 DH=64. Inputs f32, mask int32, outputs f32.
//
// Round-6 lesson: register-prefetch staging can't hide latency (vmcnt(0)
// before LDS-commit; 14% occupancy). Round-7: m97 recipe — async
// global_load_lds(16B) staging, single LDS buffer (16 KB), 2-barrier K-loop.
// f32->bf16 conversion hoisted into a cvt pass writing into the (not yet
// written) pos region of d_out; pos_kernel moved after the QKV GEMM.
// q/k now stored row-major [8192][512] (coalesced epilogue; attn adapted).
//
// Dispatches: cvt, transpose, gemm_glds<4>(QKV fused), pos, attn,
//             gemm_glds<2>(final).
//
// MFMA 16x16x32 bf16 layouts (verified m89/m91 + round-3 scalar oracle):
//   A: lane holds A[m=lane&15][k=(lane>>4)*8+j]   (16B contiguous)
//   B: lane holds B[k=(lane>>4)*8+j][n=lane&15]   (contiguous, B stored n-major)
//   C/D: col=lane&15, row=(lane>>4)*4+reg
// LDS tiles unpadded [rows][32] bf16 (64 B row): b128 frag reads hit
// 8 uniform bank-starts x 8 lanes (minimum phases); glds lane-contiguity
// matches this layout exactly (lane l -> base + l*16 B).
// ============================================================================

typedef __bf16 bf16_t;
typedef __bf16 bf16x4 __attribute__((ext_vector_type(4)));
typedef __bf16 bf16x8 __attribute__((ext_vector_type(8)));
typedef float  f32x4  __attribute__((ext_vector_type(4)));
typedef unsigned int u32;

#define NB    32
#define NSEQ  256
#define DMODEL 512
#define NH    8
#define DHEAD 64
#define M_ROWS (NB * NSEQ)              // 8192
#define ATTED_ELEMS (M_ROWS * DMODEL)   // 4,194,304 f32
#define HEAD_T_ELEMS 4194304            // one [8192x512]-class tensor

// ws layout (bf16 elements); total 17,825,792 elems = 35.7 MB
#define WS_WT    0          // 4 * 512*512
#define WS_QH    1048576    // q(row-major): +0, k(row-major): +4.19M, vT: +8.39M
#define WS_ATTW  13631488   // [B*N, DM]

// async global->LDS, 16 B per lane; lds dest = wave-uniform base + lane*16
__device__ inline void glds16(const bf16_t* g, bf16_t* l) {
  __builtin_amdgcn_global_load_lds(
      (const __attribute__((address_space(1))) u32*)g,
      (__attribute__((address_space(3))) u32*)l, 16, 0, 0);
}

// ---------------------------------------------------------------------------
// q,k,v f32 -> bf16 row-major, into d_out pos-region scratch (dead until pos).
__global__ __launch_bounds__(256) void cvt_kernel(
    const float* __restrict__ q, const float* __restrict__ k,
    const float* __restrict__ v, bf16_t* __restrict__ dst) {
  int z = blockIdx.y;
  const float* s = (z == 0) ? q : (z == 1) ? k : v;
  size_t i = ((size_t)blockIdx.x * 256 + threadIdx.x) * 4;
  float4 x = *(const float4*)(s + i);
  bf16x4 y;
  y[0] = (bf16_t)x.x; y[1] = (bf16_t)x.y; y[2] = (bf16_t)x.z; y[3] = (bf16_t)x.w;
  *(bf16x4*)(dst + (size_t)z * HEAD_T_ELEMS + i) = y;
}

// ---------------------------------------------------------------------------
// W (f32, [k][n]) -> WT (bf16, [n][k]), 64x64 LDS tiles, both sides coalesced.
__global__ __launch_bounds__(256) void transpose_kernel(
    const float* __restrict__ W0, const float* __restrict__ W1,
    const float* __restrict__ W2, const float* __restrict__ W3,
    bf16_t* __restrict__ wt) {
  __shared__ float T_s[64 * 65];
  int tid = threadIdx.x;
  int m = blockIdx.z;
  const float* W = (m == 0) ? W0 : (m == 1) ? W1 : (m == 2) ? W2 : W3;
  bf16_t* WT = wt + m * (DMODEL * DMODEL);
  int k0 = blockIdx.x * 64, n0 = blockIdx.y * 64;
#pragma unroll
  for (int i = 0; i < 16; i++) {
    int idx = tid + i * 256;
    int r = idx >> 6, c = idx & 63;
    T_s[r * 65 + c] = W[(size_t)(k0 + r) * DMODEL + n0 + c];
  }
  __syncthreads();
#pragma unroll
  for (int i = 0; i < 16; i++) {
    int idx = tid + i * 256;
    int r = idx >> 6, c = idx & 63;
    WT[(size_t)(n0 + r) * DMODEL + k0 + c] = (bf16_t)T_s[c * 65 + r];
  }
}

// ---------------------------------------------------------------------------
// ps[b,i,j]; one block per (b,i), thread j. Writes all 8 head copies (f32).
__global__ __launch_bounds__(256) void pos_kernel(
    const float* __restrict__ box, const float* __restrict__ Wbox,
    const float* __restrict__ bbox, float* __restrict__ pos_out) {
  __shared__ float wb[64];
  __shared__ float bb;
  int tid = threadIdx.x;
  if (tid < 64) wb[tid] = Wbox[tid];
  if (tid == 0) bb = bbox[0];
  __syncthreads();

  int bx = blockIdx.x;
  int b = bx >> 8, i = bx & 255, j = tid;

  float4 bi = *(const float4*)(box + (size_t)(b * NSEQ + i) * 4);
  float4 bj = *(const float4*)(box + (size_t)(b * NSEQ + j) * 4);

  float cxi = (bi.x + bi.z) * 0.5f, cyi = (bi.y + bi.w) * 0.5f;
  float wi = bi.z - bi.x + 1.0f,    hi = bi.w - bi.y + 1.0f;
  float cxj = (bj.x + bj.z) * 0.5f, cyj = (bj.y + bj.w) * 0.5f;
  float wj = bj.z - bj.x + 1.0f,    hj = bj.w - bj.y + 1.0f;

  float dx = __logf(fmaxf(fabsf((cxi - cxj) / wi), 1e-3f));
  float dy = __logf(fmaxf(fabsf((cyi - cyj) / hi), 1e-3f));
  float dw = __logf(wi / wj);
  float dh = __logf(hi / hj);

  // dim_mat[f] = 1000^(-f/8)
  const float dim_mat[8] = {1.0f, 0.42169650342f, 0.177827941f, 0.074989421f,
                            0.0316227766f, 0.0133352143f, 0.00562341325f, 0.00237137371f};
  float p4[4] = {dx, dy, dw, dh};
  float acc = bb;
#pragma unroll
  for (int c = 0; c < 4; c++) {
    float base = 100.0f * p4[c];
#pragma unroll
    for (int f = 0; f < 8; f++) {
      float sn, cs;
      __sincosf(base * dim_mat[f], &sn, &cs);
      acc += sn * wb[c * 8 + f] + cs * wb[32 + c * 8 + f];
    }
  }
  float pv = fmaxf(acc, 0.0f);
  size_t base_bi = ((size_t)b * NH * NSEQ + i) * NSEQ + j;  // h=0 slot
#pragma unroll
  for (int h = 0; h < NH; h++)
    pos_out[base_bi + (size_t)h * NSEQ * NSEQ] = pv;
}

// ---------------------------------------------------------------------------
// m97-style GEMM: tile ROWS x 128 (ROWS = IF*32), BK=32, async glds staging,
// single LDS buffer, 2 barriers/iter. A bf16 row-major [8192][512].
// IF=4: QKV fused (z: 0=q->row-major, 1=k->row-major, 2=v->vT scatter)
// IF=2: final (final_mode=2 -> f32 row-major atted)
template <int IF>
__global__ __launch_bounds__(256) void gemm_glds(
    const bf16_t* __restrict__ A0, const bf16_t* __restrict__ A1,
    const bf16_t* __restrict__ A2, const bf16_t* __restrict__ WTbase,
    const float* __restrict__ bias0, const float* __restrict__ bias1,
    const float* __restrict__ bias2,
    bf16_t* __restrict__ outb, float* __restrict__ outf, int final_mode) {
  constexpr int ROWS = IF * 32;
  __shared__ bf16_t A_s[ROWS * 32];
  __shared__ bf16_t B_s[128 * 32];

  int tid = threadIdx.x;
  int wave = tid >> 6, lane = tid & 63, quad = lane >> 4, l16 = lane & 15;
  int wm = wave >> 1, wn = wave & 1;
  int bm = blockIdx.x, bn = blockIdx.y, z = blockIdx.z;

  const bf16_t* A = (z == 0) ? A0 : (z == 1) ? A1 : A2;
  const float* bias = (z == 0) ? bias0 : (z == 1) ? bias1 : bias2;
  const bf16_t* WT = WTbase + (size_t)(final_mode == 2 ? 3 : z) * 262144;
  int mode = (final_mode == 2) ? 2 : ((z == 2) ? 1 : 0);

  // per-lane global offsets for staging (row = r0 + lane/4, seg = lane%4)
  int srow = lane >> 2, sseg = (lane & 3) * 8;

  f32x4 acc[IF][4];
#pragma unroll
  for (int i = 0; i < IF; i++)
#pragma unroll
    for (int j = 0; j < 4; j++) acc[i][j] = (f32x4){0.f, 0.f, 0.f, 0.f};

  for (int kk = 0; kk < 16; kk++) {
    int k0 = kk * 32;
    // async stage A (ROWS x 32) and B (128 x 32): 16-row packs, 1 KB/inst
#pragma unroll
    for (int i = 0; i < ROWS / 64; i++) {
      int r0 = (wave * (ROWS / 64) + i) * 16;
      glds16(A + (size_t)(bm * ROWS + r0 + srow) * DMODEL + k0 + sseg,
             A_s + r0 * 32);
    }
#pragma unroll
    for (int i = 0; i < 2; i++) {
      int r0 = (wave * 2 + i) * 16;
      glds16(WT + (size_t)(bn * 128 + r0 + srow) * DMODEL + k0 + sseg,
             B_s + r0 * 32);
    }
    __syncthreads();   // drains glds queue (vmcnt) -> LDS valid

    bf16x8 a[IF], b[4];
#pragma unroll
    for (int i = 0; i < IF; i++)
      a[i] = *(const bf16x8*)(A_s + (wm * (IF * 16) + i * 16 + l16) * 32 + quad * 8);
#pragma unroll
    for (int j = 0; j < 4; j++)
      b[j] = *(const bf16x8*)(B_s + (wn * 64 + j * 16 + l16) * 32 + quad * 8);
#pragma unroll
    for (int i = 0; i < IF; i++)
#pragma unroll
      for (int j = 0; j < 4; j++)
        acc[i][j] = __builtin_amdgcn_mfma_f32_16x16x32_bf16(a[i], b[j], acc[i][j], 0, 0, 0);
    __syncthreads();   // all LDS reads done before next stage overwrites
  }

  // epilogue
#pragma unroll
  for (int j = 0; j < 4; j++) {
    int gc = bn * 128 + wn * 64 + j * 16 + l16;
    float bs = bias[gc];
#pragma unroll
    for (int i = 0; i < IF; i++) {
#pragma unroll
      for (int r = 0; r < 4; r++) {
        int gm = bm * ROWS + wm * (IF * 16) + i * 16 + quad * 4 + r;
        float val = acc[i][j][r] + bs;
        if (mode == 2) {
          outf[(size_t)gm * DMODEL + gc] = val;
        } else if (mode == 0) {   // q,k: row-major bf16
          outb[(size_t)z * HEAD_T_ELEMS + (size_t)gm * DMODEL + gc] = (bf16_t)val;
        } else {                  // v: [b][h][d][n] transposed-head
          int b = gm >> 8, n = gm & 255, h = gc >> 6, d = gc & 63;
          outb[2 * HEAD_T_ELEMS +
               ((size_t)(b * NH + h) * DHEAD + d) * NSEQ + n] = (bf16_t)val;
        }
      }
    }
  }
}

// ---------------------------------------------------------------------------
// Attention: block = (qt, h, b), 4 waves x 16 q-rows. qh/kh row-major
// [8192][512] (head offset h*64). K tile staged in LDS [256][72] (padded,
// bank-uniform); P aliases it after phase A as [64][264].
__global__ __launch_bounds__(256) void attn_kernel(
    const bf16_t* __restrict__ qh, const bf16_t* __restrict__ kh,
    const bf16_t* __restrict__ vT, const float* __restrict__ pos,
    const int* __restrict__ mask, bf16_t* __restrict__ attw) {
  __shared__ bf16_t KP_s[256 * 72];   // 36,864 B; P (64x264) aliases it

  int tid = threadIdx.x;
  int wave = tid >> 6, lane = tid & 63, quad = lane >> 4, l16 = lane & 15;
  int qt = blockIdx.x, h = blockIdx.y, b = blockIdx.z;

  const bf16_t* qb = qh + (size_t)(b * NSEQ) * DMODEL + h * DHEAD;  // row-major
  const bf16_t* kb = kh + (size_t)(b * NSEQ) * DMODEL + h * DHEAD;  // row-major
  const bf16_t* vb = vT + (size_t)(b * NH + h) * DHEAD * NSEQ;
  const float* pb = pos + (size_t)b * NH * NSEQ * NSEQ;  // h=0 copy (identical)
  const int* mrow = mask + b * NSEQ;

  int m0 = qt * 64 + wave * 16;

  // hoisted: Q frags + mask row (overlap K staging latency)
  bf16x8 a0 = *(const bf16x8*)(qb + (size_t)(m0 + l16) * DMODEL + quad * 8);
  bf16x8 a1 = *(const bf16x8*)(qb + (size_t)(m0 + l16) * DMODEL + 32 + quad * 8);
  int mk[16];
#pragma unroll
  for (int t = 0; t < 16; t++) mk[t] = mrow[t * 16 + l16];

  // stage K tile: 256 rows (stride DMODEL) x 64 d -> rows padded to 72
#pragma unroll
  for (int i = 0; i < 8; i++) {
    int flat = tid + i * 256;
    int row = flat >> 3, seg = flat & 7;
    *(bf16x8*)(KP_s + row * 72 + seg * 8) =
        *(const bf16x8*)(kb + (size_t)row * DMODEL + seg * 8);
  }
  __syncthreads();

  // Phase A: S = qh @ kh^T (16 key-tiles, K=64 as two 32-chunks) from LDS
  f32x4 s[16];
#pragma unroll
  for (int t = 0; t < 16; t++) s[t] = (f32x4){0.f, 0.f, 0.f, 0.f};
#pragma unroll
  for (int t = 0; t < 16; t++) {
    const bf16_t* krow = KP_s + (t * 16 + l16) * 72;
    bf16x8 b0 = *(const bf16x8*)(krow + quad * 8);
    bf16x8 b1 = *(const bf16x8*)(krow + 32 + quad * 8);
    s[t] = __builtin_amdgcn_mfma_f32_16x16x32_bf16(a0, b0, s[t], 0, 0, 0);
    s[t] = __builtin_amdgcn_mfma_f32_16x16x32_bf16(a1, b1, s[t], 0, 0, 0);
  }

  // Phase B: scale + pos + mask (C-layout: row=quad*4+r, col=t*16+l16)
#pragma unroll
  for (int t = 0; t < 16; t++) {
    int gj = t * 16 + l16;
#pragma unroll
    for (int r = 0; r < 4; r++) {
      int gr = m0 + quad * 4 + r;
      float v = s[t][r] * 0.125f + pb[(size_t)gr * NSEQ + gj];
      s[t][r] = mk[t] ? -1e9f : v;
    }
  }

  // Register softmax: each row lives across the 16 lanes of a quad.
  float inv[4];
#pragma unroll
  for (int r = 0; r < 4; r++) {
    float m = -1e30f;
#pragma unroll
    for (int t = 0; t < 16; t++) m = fmaxf(m, s[t][r]);
    m = fmaxf(m, __shfl_xor(m, 1));
    m = fmaxf(m, __shfl_xor(m, 2));
    m = fmaxf(m, __shfl_xor(m, 4));
    m = fmaxf(m, __shfl_xor(m, 8));
    float sum = 0.f;
#pragma unroll
    for (int t = 0; t < 16; t++) {
      float e = __expf(s[t][r] - m);
      s[t][r] = e;
      sum += e;
    }
    sum += __shfl_xor(sum, 1);
    sum += __shfl_xor(sum, 2);
    sum += __shfl_xor(sum, 4);
    sum += __shfl_xor(sum, 8);
    inv[r] = 1.0f / sum;
  }

  __syncthreads();   // all phase-A K_s reads complete before P overwrites

  // P (bf16) -> KP_s as [64][264] row-major (A-operand readable)
#pragma unroll
  for (int t = 0; t < 16; t++) {
    int gj = t * 16 + l16;
#pragma unroll
    for (int r = 0; r < 4; r++)
      KP_s[(wave * 16 + quad * 4 + r) * 264 + gj] = (bf16_t)(s[t][r] * inv[r]);
  }
  // no barrier: each wave reads back only its own 16 P rows

  // Phase C: O = P @ V (V pre-transposed [DH][N], direct global B-frags)
  f32x4 o[4];
#pragma unroll
  for (int t2 = 0; t2 < 4; t2++) o[t2] = (f32x4){0.f, 0.f, 0.f, 0.f};
#pragma unroll
  for (int kk = 0; kk < 8; kk++) {
    bf16x8 pa = *(const bf16x8*)(KP_s + (wave * 16 + l16) * 264 + kk * 32 + quad * 8);
#pragma unroll
    for (int t2 = 0; t2 < 4; t2++) {
      bf16x8 vv = *(const bf16x8*)(vb + (size_t)(t2 * 16 + l16) * NSEQ + kk * 32 + quad * 8);
      o[t2] = __builtin_amdgcn_mfma_f32_16x16x32_bf16(pa, vv, o[t2], 0, 0, 0);
    }
  }

  // Epilogue: attw[(b*256+q)*512 + h*64+d]
#pragma unroll
  for (int t2 = 0; t2 < 4; t2++) {
    int d = t2 * 16 + l16;
#pragma unroll
    for (int r = 0; r < 4; r++) {
      int gr = m0 + quad * 4 + r;
      attw[(size_t)(b * NSEQ + gr) * DMODEL + h * DHEAD + d] = (bf16_t)o[t2][r];
    }
  }
}

// ---------------------------------------------------------------------------
extern "C" void kernel_launch(void* const* d_in, const int* in_sizes, int n_in,
                              void* d_out, int out_size, void* d_ws, size_t ws_size,
                              hipStream_t stream) {
  const float* v    = (const float*)d_in[0];
  const float* k    = (const float*)d_in[1];
  const float* q    = (const float*)d_in[2];
  const float* box  = (const float*)d_in[3];
  const int*   mask = (const int*)d_in[4];
  // d_in[5] = fg (always 2; branch fixed)
  const float* Wq   = (const float*)d_in[6];
  const float* bq   = (const float*)d_in[7];
  const float* Wk   = (const float*)d_in[8];
  const float* bk   = (const float*)d_in[9];
  const float* Wv   = (const float*)d_in[10];
  const float* bv   = (const float*)d_in[11];
  const float* Wm   = (const float*)d_in[12];
  const float* bm   = (const float*)d_in[13];
  const float* Wbox = (const float*)d_in[14];
  const float* bbox = (const float*)d_in[15];

  float* out  = (float*)d_out;
  bf16_t* ws  = (bf16_t*)d_ws;
  bf16_t* WT   = ws + WS_WT;
  bf16_t* qh   = ws + WS_QH;                 // q row-major; k at +1 slot; vT +2
  bf16_t* khw  = qh + 1 * HEAD_T_ELEMS;
  bf16_t* vTp  = qh + 2 * HEAD_T_ELEMS;
  bf16_t* attw = ws + WS_ATTW;
  float* pos  = out + ATTED_ELEMS;           // pos_scores region (f32)
  bf16_t* cvtb = (bf16_t*)pos;               // scratch: dead until pos_kernel

  cvt_kernel<<<dim3(4096, 3), dim3(256), 0, stream>>>(q, k, v, cvtb);
  transpose_kernel<<<dim3(8, 8, 4), dim3(256), 0, stream>>>(Wq, Wk, Wv, Wm, WT);
  gemm_glds<4><<<dim3(64, 4, 3), dim3(256), 0, stream>>>(
      cvtb, cvtb + HEAD_T_ELEMS, cvtb + 2 * HEAD_T_ELEMS, WT,
      bq, bk, bv, qh, out, 0);
  pos_kernel<<<dim3(NB * NSEQ), dim3(256), 0, stream>>>(box, Wbox, bbox, pos);
  attn_kernel<<<dim3(NSEQ / 64, NH, NB), dim3(256), 0, stream>>>(
      qh, khw, vTp, pos, mask, attw);
  gemm_glds<2><<<dim3(128, 4, 1), dim3(256), 0, stream>>>(
      attw, attw, attw, WT, bm, bm, bm, qh, out, 2);
}